// Round 2
// baseline (145.642 us; speedup 1.0000x reference)
//
#include <hip/hip_runtime.h>
#include <cmath>

#define NROWS 4096
#define TLEN  1024
#define LT0   895      // first t stored for level/trend tail (COND-1)
#define ST0   889      // first t stored for seas tail (889 = 896-7)
#define LTN   129
#define STN   135
#define PR_F4 (NROWS * 129 * 14)   // pr float4 count

__device__ __forceinline__ float sigmoidf_(float x) {
    return 1.0f / (1.0f + expf(-x));
}

// 64 single-wave blocks; each lane owns one row. Query is staged per
// 64-t window through an XOR-swizzled LDS tile so global loads/stores are
// coalesced; the 64-step recurrence runs fully in registers.
__global__ __launch_bounds__(64, 1)
void es_scan(const float* __restrict__ query,
             const float* __restrict__ params,
             float* __restrict__ sm,
             float* __restrict__ diffs,
             float* __restrict__ Lt,   // [129][4096]
             float* __restrict__ Tt,   // [129][4096]
             float* __restrict__ St)   // [135][4096]
{
    __shared__ float qt[2][64 * 64];
    const int lam = threadIdx.x;
    const int rowbase = blockIdx.x * 64;
    const int n = rowbase + lam;

    const float* pp = params + n * 12;
    float L = pp[0];
    const float a = sigmoidf_(pp[1]);
    float B = pp[2];
    const float b = sigmoidf_(pp[3]);
    const float c = pp[4];                 // NOT sigmoided (reference)
    const float ia = 1.0f - a, ib = 1.0f - b, ic = 1.0f - c;
    float sbuf[7];
    #pragma unroll
    for (int j = 0; j < 7; ++j) sbuf[j] = sigmoidf_(pp[5 + j]);

    const int rsub = lam >> 4;          // 0..3
    const int tb4  = 4 * (lam & 15);    // 0,4,...,60

    // prologue: stage window 0 into buf 0
    {
        float4 v[16];
        #pragma unroll
        for (int i = 0; i < 16; ++i)
            v[i] = *reinterpret_cast<const float4*>(
                &query[(size_t)(rowbase + 4*i + rsub) * TLEN + tb4]);
        #pragma unroll
        for (int i = 0; i < 16; ++i) {
            const int rho = 4*i + rsub;
            #pragma unroll
            for (int j = 0; j < 4; ++j) {
                const int tau = tb4 + j;
                qt[0][tau*64 + (rho ^ (tau & 31))] = ((const float*)&v[i])[j];
            }
        }
    }

    float dsum = 0.0f;

    for (int w = 0; w < 16; ++w) {
        const int p = w & 1;
        float* bufc = qt[p];
        float* bufn = qt[p ^ 1];

        // (1) prefetch next window into regs (issue early, write late)
        float4 nxt[16];
        if (w < 15) {
            #pragma unroll
            for (int i = 0; i < 16; ++i)
                nxt[i] = *reinterpret_cast<const float4*>(
                    &query[(size_t)(rowbase + 4*i + rsub) * TLEN + (w+1)*64 + tb4]);
        }

        // (2) batch-read this window's y BEFORE any in-place write, so the
        //     compiler can pipeline the 64 ds_reads (no alias upstream).
        float y[64];
        #pragma unroll
        for (int t = 0; t < 64; ++t)
            y[t] = bufc[t*64 + (lam ^ (t & 31))];

        // (3) 64 sequential steps, register-resident; sm written in place
        #pragma unroll
        for (int t = 0; t < 64; ++t) {
            const float yy = y[t];
            const float pred  = L + B;
            const float level = fmaf(a, yy, ia * pred);
            const float d     = level - L;
            dsum += fabsf(d);
            const float trend = fmaf(b, d, ib * B);
            const float e     = yy - pred;
            const float sn    = fmaf(c, e, ic * sbuf[t % 7]);
            const float smval = (yy - level) - sn;
            sbuf[t % 7] = sn;
            L = level; B = trend;
            bufc[t*64 + (lam ^ (t & 31))] = smval;
            const int tg = w*64 + t;    // wave-uniform -> scalar branches
            if (tg >= ST0) St[(size_t)(tg - ST0) * NROWS + n] = sn;
            if (tg >= LT0) {
                Lt[(size_t)(tg - LT0) * NROWS + n] = level;
                Tt[(size_t)(tg - LT0) * NROWS + n] = trend;
            }
        }
        // rotate seasonal ring left by one (64 mod 7 == 1)
        {
            float tmp = sbuf[0];
            sbuf[0]=sbuf[1]; sbuf[1]=sbuf[2]; sbuf[2]=sbuf[3];
            sbuf[3]=sbuf[4]; sbuf[4]=sbuf[5]; sbuf[5]=sbuf[6]; sbuf[6]=tmp;
        }

        // (4) flush sm tile (transposed gather) -> coalesced float4 stores
        #pragma unroll
        for (int i = 0; i < 16; ++i) {
            const int rho = 4*i + rsub;
            float4 o;
            o.x = bufc[(tb4+0)*64 + (rho ^ ((tb4+0) & 31))];
            o.y = bufc[(tb4+1)*64 + (rho ^ ((tb4+1) & 31))];
            o.z = bufc[(tb4+2)*64 + (rho ^ ((tb4+2) & 31))];
            o.w = bufc[(tb4+3)*64 + (rho ^ ((tb4+3) & 31))];
            *reinterpret_cast<float4*>(
                &sm[(size_t)(rowbase + rho) * TLEN + w*64 + tb4]) = o;
        }

        // (5) stage prefetched regs into the other buffer
        if (w < 15) {
            #pragma unroll
            for (int i = 0; i < 16; ++i) {
                const int rho = 4*i + rsub;
                #pragma unroll
                for (int j = 0; j < 4; ++j) {
                    const int tau = tb4 + j;
                    bufn[tau*64 + (rho ^ (tau & 31))] = ((const float*)&nxt[i])[j];
                }
            }
        }
    }

    diffs[n] = dsum * (1.0f / 1024.0f);
}

__global__ __launch_bounds__(256)
void es_pr(const float* __restrict__ Lt,
           const float* __restrict__ Tt,
           const float* __restrict__ St,
           float4* __restrict__ pr)
{
    const int q = blockIdx.x * 256 + threadIdx.x;
    if (q >= PR_F4) return;
    const int h4 = q % 14;
    const int r  = q / 14;
    const int s  = r % 129;
    const int n  = r / 129;

    const float L = Lt[(size_t)s * NROWS + n];
    const float T = Tt[(size_t)s * NROWS + n];

    const int hb = h4 * 4;        // h = hb..hb+3; horizon = h+1
    int m0 = hb % 7;
    int m1 = m0 + 1; if (m1 >= 7) m1 -= 7;
    int m2 = m0 + 2; if (m2 >= 7) m2 -= 7;
    int m3 = m0 + 3; if (m3 >= 7) m3 -= 7;

    float4 o;
    o.x = (L + T * (float)(hb + 1)) + St[(size_t)(s + m0) * NROWS + n];
    o.y = (L + T * (float)(hb + 2)) + St[(size_t)(s + m1) * NROWS + n];
    o.z = (L + T * (float)(hb + 3)) + St[(size_t)(s + m2) * NROWS + n];
    o.w = (L + T * (float)(hb + 4)) + St[(size_t)(s + m3) * NROWS + n];
    pr[q] = o;
}

extern "C" void kernel_launch(void* const* d_in, const int* in_sizes, int n_in,
                              void* d_out, int out_size, void* d_ws, size_t ws_size,
                              hipStream_t stream) {
    const float* query  = (const float*)d_in[0];
    const float* params = (const float*)d_in[1];

    float* out   = (float*)d_out;
    float* sm    = out;                                  // 4096*1024
    float* pr    = out + (size_t)NROWS * TLEN;           // 4096*129*56
    float* diffs = pr  + (size_t)NROWS * 129 * 56;       // 4096

    float* Lt = (float*)d_ws;                            // [129][4096]
    float* Tt = Lt + (size_t)LTN * NROWS;                // [129][4096]
    float* St = Tt + (size_t)LTN * NROWS;                // [135][4096]

    hipLaunchKernelGGL(es_scan, dim3(64), dim3(64), 0, stream,
                       query, params, sm, diffs, Lt, Tt, St);
    hipLaunchKernelGGL(es_pr, dim3(PR_F4 / 256), dim3(256), 0, stream,
                       Lt, Tt, St, (float4*)pr);
}

// Round 3
// 49.240 us; speedup vs baseline: 2.9578x; 2.9578x over previous
//
#include <hip/hip_runtime.h>
#include <cmath>

#define NROWS 4096
#define TLEN  1024
#define KCH   32           // chunks per row
#define RPB   8            // rows per block
#define LT0   895
#define ST0   889
#define LTN   129
#define STN   135
#define PR_F4 (NROWS * 129 * 14)

__device__ __forceinline__ float sigmoidf_(float x) {
    return 1.0f / (1.0f + expf(-x));
}

__device__ __forceinline__ float f4c(const float4& v, int k) {
    switch (k & 3) { case 0: return v.x; case 1: return v.y; case 2: return v.z; default: return v.w; }
}

// One block = 8 rows x 32 chunks of 32 timesteps. Blocked parallel scan:
// LB recurrence is linear with per-row constant 2x2 matrix; seasonal is 7
// scalar linear lag-1 chains. 512 blocks x 256 threads -> full-GPU TLP.
__global__ __launch_bounds__(256, 2)
void es_scan(const float* __restrict__ query,
             const float* __restrict__ params,
             float* __restrict__ sm,
             float* __restrict__ diffs,
             float* __restrict__ Lt,   // [NROWS][129]
             float* __restrict__ Tt,   // [NROWS][129]
             float* __restrict__ St)   // [NROWS][135]
{
    __shared__ float lds_P[RPB * 65];      // r*65 + 2k + b   (pad to break 8-way)
    __shared__ float lds_start[RPB * 65];  // r*65 + 2k + b
    __shared__ float lds_q[RPB * 225];     // r*225 + k*7 + g (g = global phase)
    __shared__ float lds_dsum[RPB * 33];   // r*33 + k
    __shared__ float lds_par[RPB * 16];    // {L0,B0,ia,A21,A22,ic,is[7]}

    const int tid = threadIdx.x;
    const int r = tid >> 5;          // local row 0..7
    const int k = tid & 31;          // chunk 0..31
    const int n = blockIdx.x * RPB + r;

    const float* pp = params + (size_t)n * 12;
    const float a  = sigmoidf_(pp[1]);
    const float b  = sigmoidf_(pp[3]);
    const float c  = pp[4];                   // raw (reference does NOT sigmoid)
    const float ia = 1.0f - a, ib = 1.0f - b, ic = 1.0f - c;

    // per-thread y chunk (32 floats in regs)
    float4 yv[8];
    {
        const float4* qv = reinterpret_cast<const float4*>(query + (size_t)n * TLEN + k * 32);
        #pragma unroll
        for (int i = 0; i < 8; ++i) yv[i] = qv[i];
    }

    // ---- phase 1: affine partial of LB chunk (zero init) ----
    {
        float L = 0.0f, B = 0.0f;
        #pragma unroll
        for (int j = 0; j < 32; ++j) {
            const float yy = f4c(yv[j >> 2], j);
            const float pred  = L + B;
            const float level = fmaf(a, yy, ia * pred);
            const float trend = fmaf(b, level - L, ib * B);
            L = level; B = trend;
        }
        lds_P[r * 65 + 2 * k]     = L;
        lds_P[r * 65 + 2 * k + 1] = B;
    }
    if (k == 0) {
        float* par = &lds_par[r * 16];
        par[0] = pp[0];                  // L0
        par[1] = pp[2];                  // B0
        par[2] = ia;                     // A00 = A01
        par[3] = -(a * b);               // A21
        par[4] = ib + b * ia;            // A22
        par[5] = ic;
        #pragma unroll
        for (int l = 0; l < 7; ++l) par[6 + l] = sigmoidf_(pp[5 + l]);
    }
    __syncthreads();

    // ---- phase 2: per-row serial scan of 32 chunk summaries (8 threads) ----
    if (tid < 8) {
        const float* par = &lds_par[tid * 16];
        float m00 = par[2], m01 = par[2], m10 = par[3], m11 = par[4];
        #pragma unroll
        for (int s = 0; s < 5; ++s) {    // M = A^32
            const float t00 = m00 * m00 + m01 * m10;
            const float t01 = m00 * m01 + m01 * m11;
            const float t10 = m10 * m00 + m11 * m10;
            const float t11 = m10 * m01 + m11 * m11;
            m00 = t00; m01 = t01; m10 = t10; m11 = t11;
        }
        float P0[32], P1[32];
        #pragma unroll
        for (int kk = 0; kk < 32; ++kk) {
            P0[kk] = lds_P[tid * 65 + 2 * kk];
            P1[kk] = lds_P[tid * 65 + 2 * kk + 1];
        }
        float s0 = par[0], s1 = par[1];
        #pragma unroll
        for (int kk = 0; kk < 32; ++kk) {
            lds_start[tid * 65 + 2 * kk]     = s0;
            lds_start[tid * 65 + 2 * kk + 1] = s1;
            const float t0 = m00 * s0 + m01 * s1 + P0[kk];
            const float t1 = m10 * s0 + m11 * s1 + P1[kk];
            s0 = t0; s1 = t1;
        }
    }
    __syncthreads();

    const float st0 = lds_start[r * 65 + 2 * k];
    const float st1 = lds_start[r * 65 + 2 * k + 1];

    // ---- phase 3: recompute chunk, seasonal partials + |dL| partial ----
    {
        float L = st0, B = st1, dsum = 0.0f;
        float q[7] = {0,0,0,0,0,0,0};
        #pragma unroll
        for (int j = 0; j < 32; ++j) {
            const float yy = f4c(yv[j >> 2], j);
            const float pred  = L + B;
            const float level = fmaf(a, yy, ia * pred);
            const float d     = level - L;
            dsum += fabsf(d);
            const float trend = fmaf(b, d, ib * B);
            const float e     = yy - pred;
            q[j % 7] = fmaf(ic, q[j % 7], c * e);
            L = level; B = trend;
        }
        const int kp = (4 * k) % 7;
        #pragma unroll
        for (int l = 0; l < 7; ++l) {
            int g = kp + l; if (g >= 7) g -= 7;
            lds_q[r * 225 + k * 7 + g] = q[l];
        }
        lds_dsum[r * 33 + k] = dsum;
    }
    __syncthreads();

    // ---- phase 4: seasonal chain scan (56 threads) + diffs reduce (8) ----
    if (tid < 56) {
        const int rr = tid / 7, p = tid % 7;
        const float icc = lds_par[rr * 16 + 5];
        float ic2 = icc * icc;
        const float ic4 = ic2 * ic2;
        const float ic5 = ic4 * icc;
        float v = lds_par[rr * 16 + 6 + p];
        float qq[32];
        #pragma unroll
        for (int kk = 0; kk < 32; ++kk) qq[kk] = lds_q[rr * 225 + kk * 7 + p];
        int l = p;
        #pragma unroll
        for (int kk = 0; kk < 32; ++kk) {
            const float m = (l < 4) ? ic5 : ic4;   // #occurrences of this phase in chunk
            const float nv = fmaf(m, v, qq[kk]);
            lds_q[rr * 225 + kk * 7 + p] = v;      // phase-start entering chunk kk
            v = nv;
            l += 3; if (l >= 7) l -= 7;            // local phase of p in next chunk
        }
    } else if (tid < 64) {
        const int rr = tid - 56;
        float s = 0.0f;
        #pragma unroll
        for (int kk = 0; kk < 32; ++kk) s += lds_dsum[rr * 33 + kk];
        diffs[blockIdx.x * RPB + rr] = s * (1.0f / 1024.0f);
    }
    __syncthreads();

    // ---- phase 5: final recompute, emit sm + tails ----
    {
        float sg[7];
        const int kp = (4 * k) % 7;
        #pragma unroll
        for (int l = 0; l < 7; ++l) {
            int g = kp + l; if (g >= 7) g -= 7;
            sg[l] = lds_q[r * 225 + k * 7 + g];
        }
        float L = st0, B = st1;
        float4 ov;
        float* smrow = sm + (size_t)n * TLEN + k * 32;
        #pragma unroll
        for (int j = 0; j < 32; ++j) {
            const float yy = f4c(yv[j >> 2], j);
            const float pred  = L + B;
            const float level = fmaf(a, yy, ia * pred);
            const float trend = fmaf(b, level - L, ib * B);
            const float e     = yy - pred;
            const float sn    = fmaf(ic, sg[j % 7], c * e);
            sg[j % 7] = sn;
            const float smv = (yy - level) - sn;
            switch (j & 3) { case 0: ov.x = smv; break; case 1: ov.y = smv; break;
                             case 2: ov.z = smv; break; default: ov.w = smv; }
            if ((j & 3) == 3) *reinterpret_cast<float4*>(smrow + (j - 3)) = ov;
            const int tg = k * 32 + j;
            if (tg >= ST0) St[(size_t)n * STN + tg - ST0] = sn;
            if (tg >= LT0) {
                Lt[(size_t)n * LTN + tg - LT0] = level;
                Tt[(size_t)n * LTN + tg - LT0] = trend;
            }
            L = level; B = trend;
        }
    }
}

__global__ __launch_bounds__(256)
void es_pr(const float* __restrict__ Lt,
           const float* __restrict__ Tt,
           const float* __restrict__ St,
           float4* __restrict__ pr)
{
    const int q = blockIdx.x * 256 + threadIdx.x;
    if (q >= PR_F4) return;
    const int h4 = q % 14;
    const int rr = q / 14;
    const int s  = rr % 129;
    const int n  = rr / 129;

    const float L = Lt[(size_t)n * LTN + s];
    const float T = Tt[(size_t)n * LTN + s];
    const float* stn = St + (size_t)n * STN + s;

    const int hb = h4 * 4;
    int m0 = hb % 7;
    int m1 = m0 + 1; if (m1 >= 7) m1 -= 7;
    int m2 = m0 + 2; if (m2 >= 7) m2 -= 7;
    int m3 = m0 + 3; if (m3 >= 7) m3 -= 7;

    float4 o;
    o.x = (L + T * (float)(hb + 1)) + stn[m0];
    o.y = (L + T * (float)(hb + 2)) + stn[m1];
    o.z = (L + T * (float)(hb + 3)) + stn[m2];
    o.w = (L + T * (float)(hb + 4)) + stn[m3];
    pr[q] = o;
}

extern "C" void kernel_launch(void* const* d_in, const int* in_sizes, int n_in,
                              void* d_out, int out_size, void* d_ws, size_t ws_size,
                              hipStream_t stream) {
    const float* query  = (const float*)d_in[0];
    const float* params = (const float*)d_in[1];

    float* out   = (float*)d_out;
    float* sm    = out;                                  // 4096*1024
    float* pr    = out + (size_t)NROWS * TLEN;           // 4096*129*56
    float* diffs = pr  + (size_t)NROWS * 129 * 56;       // 4096

    float* Lt = (float*)d_ws;                            // [4096][129]
    float* Tt = Lt + (size_t)NROWS * LTN;
    float* St = Tt + (size_t)NROWS * LTN;                // [4096][135]

    hipLaunchKernelGGL(es_scan, dim3(NROWS / RPB), dim3(256), 0, stream,
                       query, params, sm, diffs, Lt, Tt, St);
    hipLaunchKernelGGL(es_pr, dim3(PR_F4 / 256), dim3(256), 0, stream,
                       Lt, Tt, St, (float4*)pr);
}

// Round 4
// 36.156 us; speedup vs baseline: 4.0281x; 1.3619x over previous
//
#include <hip/hip_runtime.h>
#include <cmath>

#define NROWS 4096
#define TLEN  1024
#define RPB   8            // rows per block
#define LT0   895
#define ST0   889
#define LTN   129
#define STN   135
#define PRV4R 1806         // float4 per row of pr = 129*56/4
#define PRV4B (RPB * PRV4R)

__device__ __forceinline__ float sigmoidf_(float x) {
    return 1.0f / (1.0f + expf(-x));
}

__device__ __forceinline__ float f4c(const float4& v, int k) {
    switch (k & 3) { case 0: return v.x; case 1: return v.y; case 2: return v.z; default: return v.w; }
}

// One block = 8 rows x 32 chunks of 32 timesteps. Blocked parallel scan
// (LB recurrence is linear, 2x2 matrix; seasonal = 7 scalar lag-1 chains),
// then pr is emitted directly from LDS-resident tails (no ws round-trip).
__global__ __launch_bounds__(256, 2)
void es_fused(const float* __restrict__ query,
              const float* __restrict__ params,
              float* __restrict__ sm,
              float* __restrict__ diffs,
              float4* __restrict__ pr4)
{
    __shared__ float lds_P[RPB * 65];      // r*65 + 2k + b
    __shared__ float lds_start[RPB * 65];
    __shared__ float lds_q[RPB * 225];     // r*225 + k*7 + g (global phase)
    __shared__ float lds_dsum[RPB * 33];
    __shared__ float lds_par[RPB * 16];    // {L0,B0,ia,A21,A22,ic,is[7]}
    __shared__ float Ltl[RPB * 132];       // level  t=895..1023
    __shared__ float Ttl[RPB * 132];       // trend  t=895..1023
    __shared__ float Stl[RPB * 136];       // seas   t=889..1023

    const int tid = threadIdx.x;
    const int r = tid >> 5;          // local row 0..7
    const int k = tid & 31;          // chunk 0..31
    const int n = blockIdx.x * RPB + r;

    const float* pp = params + (size_t)n * 12;
    const float a  = sigmoidf_(pp[1]);
    const float b  = sigmoidf_(pp[3]);
    const float c  = pp[4];                   // raw (reference does NOT sigmoid)
    const float ia = 1.0f - a, ib = 1.0f - b, ic = 1.0f - c;

    // per-thread y chunk (32 floats in regs)
    float4 yv[8];
    {
        const float4* qv = reinterpret_cast<const float4*>(query + (size_t)n * TLEN + k * 32);
        #pragma unroll
        for (int i = 0; i < 8; ++i) yv[i] = qv[i];
    }

    // ---- phase 1: affine partial of LB chunk (zero init) ----
    {
        float L = 0.0f, B = 0.0f;
        #pragma unroll
        for (int j = 0; j < 32; ++j) {
            const float yy = f4c(yv[j >> 2], j);
            const float pred  = L + B;
            const float level = fmaf(a, yy, ia * pred);
            const float trend = fmaf(b, level - L, ib * B);
            L = level; B = trend;
        }
        lds_P[r * 65 + 2 * k]     = L;
        lds_P[r * 65 + 2 * k + 1] = B;
    }
    if (k == 0) {
        float* par = &lds_par[r * 16];
        par[0] = pp[0];                  // L0
        par[1] = pp[2];                  // B0
        par[2] = ia;                     // A00 = A01
        par[3] = -(a * b);               // A10
        par[4] = ib + b * ia;            // A11
        par[5] = ic;
        #pragma unroll
        for (int l = 0; l < 7; ++l) par[6 + l] = sigmoidf_(pp[5 + l]);
    }
    __syncthreads();

    // ---- phase 2: per-row serial scan of 32 chunk summaries (8 threads) ----
    if (tid < 8) {
        const float* par = &lds_par[tid * 16];
        float m00 = par[2], m01 = par[2], m10 = par[3], m11 = par[4];
        #pragma unroll
        for (int s = 0; s < 5; ++s) {    // M = A^32
            const float t00 = m00 * m00 + m01 * m10;
            const float t01 = m00 * m01 + m01 * m11;
            const float t10 = m10 * m00 + m11 * m10;
            const float t11 = m10 * m01 + m11 * m11;
            m00 = t00; m01 = t01; m10 = t10; m11 = t11;
        }
        float P0[32], P1[32];
        #pragma unroll
        for (int kk = 0; kk < 32; ++kk) {
            P0[kk] = lds_P[tid * 65 + 2 * kk];
            P1[kk] = lds_P[tid * 65 + 2 * kk + 1];
        }
        float s0 = par[0], s1 = par[1];
        #pragma unroll
        for (int kk = 0; kk < 32; ++kk) {
            lds_start[tid * 65 + 2 * kk]     = s0;
            lds_start[tid * 65 + 2 * kk + 1] = s1;
            const float t0 = m00 * s0 + m01 * s1 + P0[kk];
            const float t1 = m10 * s0 + m11 * s1 + P1[kk];
            s0 = t0; s1 = t1;
        }
    }
    __syncthreads();

    const float st0 = lds_start[r * 65 + 2 * k];
    const float st1 = lds_start[r * 65 + 2 * k + 1];

    // ---- phase 3: recompute chunk; seasonal partials + |dL| partial ----
    {
        float L = st0, B = st1, dsum = 0.0f;
        float q[7] = {0,0,0,0,0,0,0};
        #pragma unroll
        for (int j = 0; j < 32; ++j) {
            const float yy = f4c(yv[j >> 2], j);
            const float pred  = L + B;
            const float level = fmaf(a, yy, ia * pred);
            const float d     = level - L;
            dsum += fabsf(d);
            const float trend = fmaf(b, d, ib * B);
            const float e     = yy - pred;
            q[j % 7] = fmaf(ic, q[j % 7], c * e);
            L = level; B = trend;
        }
        const int kp = (4 * k) % 7;      // global phase of local slot 0
        #pragma unroll
        for (int l = 0; l < 7; ++l) {
            int g = kp + l; if (g >= 7) g -= 7;
            lds_q[r * 225 + k * 7 + g] = q[l];
        }
        lds_dsum[r * 33 + k] = dsum;
    }
    __syncthreads();

    // ---- phase 4: seasonal chain scan (56 threads) + diffs reduce (8) ----
    if (tid < 56) {
        const int rr = tid / 7, p = tid % 7;
        const float icc = lds_par[rr * 16 + 5];
        const float ic2 = icc * icc;
        const float ic4 = ic2 * ic2;
        const float ic5 = ic4 * icc;
        float v = lds_par[rr * 16 + 6 + p];
        float qq[32];
        #pragma unroll
        for (int kk = 0; kk < 32; ++kk) qq[kk] = lds_q[rr * 225 + kk * 7 + p];
        int l = p;
        #pragma unroll
        for (int kk = 0; kk < 32; ++kk) {
            const float m = (l < 4) ? ic5 : ic4;   // occurrences of phase in chunk
            const float nv = fmaf(m, v, qq[kk]);
            lds_q[rr * 225 + kk * 7 + p] = v;      // phase value entering chunk kk
            v = nv;
            l += 3; if (l >= 7) l -= 7;            // local slot of p in next chunk
        }
    } else if (tid < 64) {
        const int rr = tid - 56;
        float s = 0.0f;
        #pragma unroll
        for (int kk = 0; kk < 32; ++kk) s += lds_dsum[rr * 33 + kk];
        diffs[blockIdx.x * RPB + rr] = s * (1.0f / 1024.0f);
    }
    __syncthreads();

    // ---- phase 5: final recompute; emit sm; tails -> LDS ----
    {
        float sg[7];
        const int kp = (4 * k) % 7;
        #pragma unroll
        for (int l = 0; l < 7; ++l) {
            int g = kp + l; if (g >= 7) g -= 7;
            sg[l] = lds_q[r * 225 + k * 7 + g];
        }
        float L = st0, B = st1;
        float4 ov;
        float* smrow = sm + (size_t)n * TLEN + k * 32;
        #pragma unroll
        for (int j = 0; j < 32; ++j) {
            const float yy = f4c(yv[j >> 2], j);
            const float pred  = L + B;
            const float level = fmaf(a, yy, ia * pred);
            const float trend = fmaf(b, level - L, ib * B);
            const float e     = yy - pred;
            const float sn    = fmaf(ic, sg[j % 7], c * e);
            sg[j % 7] = sn;
            const float smv = (yy - level) - sn;
            switch (j & 3) { case 0: ov.x = smv; break; case 1: ov.y = smv; break;
                             case 2: ov.z = smv; break; default: ov.w = smv; }
            if ((j & 3) == 3) *reinterpret_cast<float4*>(smrow + (j - 3)) = ov;
            const int tg = k * 32 + j;
            if (tg >= ST0) Stl[r * 136 + tg - ST0] = sn;
            if (tg >= LT0) {
                Ltl[r * 132 + tg - LT0] = level;
                Ttl[r * 132 + tg - LT0] = trend;
            }
            L = level; B = trend;
        }
    }
    __syncthreads();

    // ---- phase 6: emit pr for the block's 8 rows from LDS tails ----
    {
        float4* prb = pr4 + (size_t)blockIdx.x * PRV4B;
        #pragma unroll 4
        for (int i = 0; i < 57; ++i) {
            const int q = i * 256 + tid;
            if (q < PRV4B) {
                const int row = q / PRV4R;
                const int rem = q - row * PRV4R;
                const int s   = rem / 14;
                const int h4  = rem - s * 14;
                const float L = Ltl[row * 132 + s];
                const float T = Ttl[row * 132 + s];
                const float* stp = &Stl[row * 136 + s];
                const int hb = h4 * 4;
                int m0 = hb % 7;
                int m1 = m0 + 1; if (m1 >= 7) m1 -= 7;
                int m2 = m0 + 2; if (m2 >= 7) m2 -= 7;
                int m3 = m0 + 3; if (m3 >= 7) m3 -= 7;
                float4 o;
                o.x = fmaf(T, (float)(hb + 1), L) + stp[m0];
                o.y = fmaf(T, (float)(hb + 2), L) + stp[m1];
                o.z = fmaf(T, (float)(hb + 3), L) + stp[m2];
                o.w = fmaf(T, (float)(hb + 4), L) + stp[m3];
                prb[q] = o;
            }
        }
    }
}

extern "C" void kernel_launch(void* const* d_in, const int* in_sizes, int n_in,
                              void* d_out, int out_size, void* d_ws, size_t ws_size,
                              hipStream_t stream) {
    const float* query  = (const float*)d_in[0];
    const float* params = (const float*)d_in[1];

    float* out   = (float*)d_out;
    float* sm    = out;                                  // 4096*1024
    float* pr    = out + (size_t)NROWS * TLEN;           // 4096*129*56
    float* diffs = pr  + (size_t)NROWS * 129 * 56;       // 4096

    hipLaunchKernelGGL(es_fused, dim3(NROWS / RPB), dim3(256), 0, stream,
                       query, params, sm, diffs, (float4*)pr);
}